// Round 1
// baseline (15.515 us; speedup 1.0000x reference)
//
#include <hip/hip_runtime.h>

// Soft polygon rasterization (mode=mask), B=128, N=64, W=H=64.
// Layout: grid.x = B*4 blocks; block = 256 threads.
//   block handles one batch's 16-row chunk (16 rows x 64 cols = 1024 px).
//   thread handles 4 consecutive x pixels on one row -> float4 store.
// Edge data staged in LDS as two float4 arrays (2x ds_read_b128 per edge,
// broadcast across lanes -> conflict-free).

__global__ __launch_bounds__(256) void softpoly_kernel(
    const float* __restrict__ verts, float* __restrict__ out)
{
    __shared__ float4 e0[64];  // ax, ay, dx, dy
    __shared__ float4 e1[64];  // 1/dd, by, 1/dy, 0

    const int tid = threadIdx.x;
    const int b   = blockIdx.x >> 2;

    if (tid < 64) {
        const float2* vp = (const float2*)(verts + b * 128);
        float2 a = vp[tid];
        float2 c = vp[(tid + 1) & 63];
        float dx = c.x - a.x;
        float dy = c.y - a.y;
        float dd = fmaxf(dx * dx + dy * dy, 1e-12f);
        e0[tid] = make_float4(a.x, a.y, dx, dy);
        e1[tid] = make_float4(1.0f / dd, c.y, 1.0f / dy, 0.0f);
    }
    __syncthreads();

    const int row = ((blockIdx.x & 3) << 4) + (tid >> 4);  // 0..63
    const int xq  = (tid & 15) << 2;                       // 0,4,..,60
    const float py  = (float)row;
    const float px0 = (float)xq;

    float mind2[4] = {1e30f, 1e30f, 1e30f, 1e30f};
    int   cross[4] = {0, 0, 0, 0};

    #pragma unroll 4
    for (int n = 0; n < 64; ++n) {
        const float4 E0 = e0[n];
        const float4 E1 = e1[n];
        // y-shared terms (all 4 pixels share py)
        const float pay   = py - E0.y;          // y - ay
        const float paydy = pay * E0.w;         // (y-ay)*dy
        const bool  cond  = (E0.y > py) != (E1.y > py);
        const float xint  = fmaf(E0.z * pay, E1.z, E0.x);  // dx*(y-ay)/dy + ax
        #pragma unroll
        for (int k = 0; k < 4; ++k) {
            float px  = px0 + (float)k;
            float pax = px - E0.x;                          // x - ax
            float t   = fmaf(pax, E0.z, paydy) * E1.x;      // dot(pa,d)/dd
            t = fminf(fmaxf(t, 0.0f), 1.0f);                // clamp -> v_med3
            float ex  = fmaf(-t, E0.z, pax);
            float ey  = fmaf(-t, E0.w, pay);
            float d2  = fmaf(ex, ex, ey * ey);
            mind2[k]  = fminf(mind2[k], d2);
            cross[k] += (cond && (px < xint)) ? 1 : 0;
        }
    }

    float4 r;
    float* rp = &r.x;
    #pragma unroll
    for (int k = 0; k < 4; ++k) {
        float s = (cross[k] & 1) ? 10.0f : -10.0f;   // sign / inv_smoothness
        rp[k] = 1.0f / (1.0f + __expf(-s * mind2[k]));
    }
    ((float4*)out)[(b << 10) + (row << 4) + (tid & 15)] = r;
}

extern "C" void kernel_launch(void* const* d_in, const int* in_sizes, int n_in,
                              void* d_out, int out_size, void* d_ws, size_t ws_size,
                              hipStream_t stream) {
    const float* verts = (const float*)d_in[0];
    float* out = (float*)d_out;
    const int B = out_size / 4096;  // 64*64 pixels per image
    softpoly_kernel<<<dim3(B * 4), dim3(256), 0, stream>>>(verts, out);
}